// Round 1
// baseline (419.900 us; speedup 1.0000x reference)
//
#include <hip/hip_runtime.h>

// GAT conv forward: N=100000 nodes, E=1.6M edges (+N self loops), IN_F=128,
// OUT_F=32, HEADS=4. Pipeline (R7, 5 dispatches) — direct atomic CSR build
// replaces the 256-bucket two-level sort (hist/binmm-bin/scatter2):
//   1. memset deg
//   2. k_deg_prep: rank[e] = atomicAdd(&deg[dst],1)  +  W->W^T bf16 prep
//   3. k_scan: single-block 1024-thread exclusive scan of deg+1 -> off[]
//   4. k_scatmm (fat): blocks [0,nbBin) scatter ssrc[off[d]+1+rank[e]]=src
//      (no atomics); blocks [nbBin,+nSelf) self-loop heads ssrc[off[i]]=i;
//      blocks [.., +nGemm) h=x@W mfma bf16 + fused a_src/a_dst epilogue,
//      aS/aD PRESCALED by log2(e) so aggregate uses bare v_exp_f32.
//   5. k_aggregate: one wave per dst; scalar (SGPR) indices + saddr gathers,
//      2-deep software pipeline, f32x2 accumulate (v_pk_fma_f32), exp2f.
//      (unchanged from R6 for attribution)

#define NEG_SLOPE 0.2f
#define CHUNK 4096      // edges per scatter/deg block
#define LOG2E 1.4426950408889634f

typedef __attribute__((ext_vector_type(8))) short short8;
typedef __attribute__((ext_vector_type(4))) float f32x4;
typedef __attribute__((ext_vector_type(2))) float f32x2;

__device__ __forceinline__ unsigned int rne16(unsigned int u) {
  return (u + 0x7fffu + ((u >> 16) & 1u)) >> 16;
}
__device__ __forceinline__ unsigned int f2bf_pack(float a, float b) {
  return (rne16(__float_as_uint(b)) << 16) | (rne16(__float_as_uint(a)) & 0xffffu);
}

// blocks [0,nbBin): degree count + per-edge rank; blocks [nbBin,+64): W^T bf16
__global__ __launch_bounds__(256) void k_deg_prep(
    const int* __restrict__ ei, int* __restrict__ deg, unsigned int* __restrict__ rank,
    int E, const float* __restrict__ W, unsigned short* __restrict__ Wt, int nbBin) {
  int tid = threadIdx.x;
  if ((int)blockIdx.x >= nbBin) {
    int idx = (blockIdx.x - nbBin) * 256 + tid;   // 16384 total
    int k = idx >> 7, col = idx & 127;
    Wt[col * 128 + k] = (unsigned short)rne16(__float_as_uint(W[idx]));
    return;
  }
  int base = blockIdx.x * CHUNK;
  int n = E - base; if (n > CHUNK) n = CHUNK;
  for (int i = tid; i < n; i += 256) {
    int d = ei[E + base + i];
    rank[base + i] = (unsigned int)atomicAdd(&deg[d], 1);  // rank = slot in segment
  }
}

// single block, 1024 threads: exclusive scan of (deg[i]+1) -> off[0..Nn]
__global__ __launch_bounds__(1024) void k_scan(const int* __restrict__ deg,
                                               int* __restrict__ off, int Nn) {
  __shared__ int wsum[16];
  __shared__ int carry;
  int tid = threadIdx.x, lane = tid & 63, w = tid >> 6;
  if (tid == 0) carry = 0;
  __syncthreads();
  for (int base = 0; base < Nn; base += 1024) {
    int c0 = carry;                      // all threads read old carry pre-sync
    int i = base + tid;
    int v = (i < Nn) ? deg[i] + 1 : 0;   // +1: self loop per node
    int inc = v;
#pragma unroll
    for (int d = 1; d < 64; d <<= 1) {
      int t = __shfl_up(inc, d, 64);
      if (lane >= d) inc += t;
    }
    if (lane == 63) wsum[w] = inc;
    __syncthreads();
    int wbase = 0;
    for (int ww = 0; ww < w; ++ww) wbase += wsum[ww];
    int ex = c0 + wbase + inc - v;
    if (i < Nn) off[i] = ex;
    if (tid == 1023) carry = ex + v;     // new carry = chunk total + old
    __syncthreads();
  }
  if (tid == 0) off[Nn] = carry;
}

// FAT kernel: scatter path + self-loop path + gemm(+att) path in one dispatch.
__global__ __launch_bounds__(256) void k_scatmm(
    const int* __restrict__ ei, const unsigned int* __restrict__ rank,
    const int* __restrict__ off, int* __restrict__ ssrc, int E, int Nn,
    int nbBin, int nSelf,
    const float* __restrict__ x, const unsigned short* __restrict__ Wt,
    unsigned int* __restrict__ hb,
    const float* __restrict__ attS, const float* __restrict__ attD,
    float* __restrict__ aS, float* __restrict__ aD) {
  int tid = threadIdx.x;
  int b = blockIdx.x;

  if (b < nbBin) {
    // ---------------- edge scatter (no atomics) ----------------
    int e0 = b * CHUNK;
    int n = E - e0; if (n > CHUNK) n = CHUNK;
    for (int i = tid; i < n; i += 256) {
      int e = e0 + i;
      int src = ei[e];
      int d = ei[E + e];
      ssrc[off[d] + 1 + (int)rank[e]] = src;   // +1: self loop at segment head
    }
    return;
  }
  if (b < nbBin + nSelf) {
    // ---------------- self-loop heads ----------------
    int i0 = (b - nbBin) * CHUNK;
    for (int i = tid; i < CHUNK; i += 256) {
      int node = i0 + i;
      if (node < Nn) ssrc[off[node]] = node;
    }
    return;
  }

  // ---------------- gemm + att path ----------------
  int gbid = b - nbBin - nSelf;
  int w = tid >> 6, lane = tid & 63;
  int m = lane & 15, q = lane >> 4;
  int r0 = gbid * 64 + w * 16;
  int rowA = r0 + m; if (rowA >= Nn) rowA = Nn - 1;
  const float* xrow = x + (unsigned)rowA * 128u;

  f32x4 acc[8];
#pragma unroll
  for (int t = 0; t < 8; ++t) acc[t] = (f32x4){0.f, 0.f, 0.f, 0.f};

#pragma unroll
  for (int ks = 0; ks < 4; ++ks) {
    int k0 = ks * 32 + q * 8;
    float4 a0 = *(const float4*)(xrow + k0);
    float4 a1 = *(const float4*)(xrow + k0 + 4);
    unsigned au[4];
    au[0] = f2bf_pack(a0.x, a0.y);
    au[1] = f2bf_pack(a0.z, a0.w);
    au[2] = f2bf_pack(a1.x, a1.y);
    au[3] = f2bf_pack(a1.z, a1.w);
    short8 af = *(short8*)au;
#pragma unroll
    for (int t = 0; t < 8; ++t) {
      short8 bf = *(const short8*)(Wt + (unsigned)(t * 16 + m) * 128u + k0);
      acc[t] = __builtin_amdgcn_mfma_f32_16x16x32_bf16(af, bf, acc[t], 0, 0, 0);
    }
  }

  // att vector slices owned by this lane: head u cols 32u+m and 32u+m+16
  float sSa[4], sSb[4], sDa[4], sDb[4];
#pragma unroll
  for (int u = 0; u < 4; ++u) {
    sSa[u] = attS[u * 32 + m]; sSb[u] = attS[u * 32 + m + 16];
    sDa[u] = attD[u * 32 + m]; sDb[u] = attD[u * 32 + m + 16];
  }

  // C layout: col = m, row = q*4 + reg
#pragma unroll
  for (int r = 0; r < 4; ++r) {
    int rowo = r0 + q * 4 + r;
    bool ok = rowo < Nn;
    if (ok) {
#pragma unroll
      for (int u = 0; u < 4; ++u)
        hb[(unsigned)rowo * 64u + u * 16 + m] = f2bf_pack(acc[2 * u][r], acc[2 * u + 1][r]);
    }
#pragma unroll
    for (int u = 0; u < 4; ++u) {
      float pS = acc[2 * u][r] * sSa[u] + acc[2 * u + 1][r] * sSb[u];
      float pD = acc[2 * u][r] * sDa[u] + acc[2 * u + 1][r] * sDb[u];
#pragma unroll
      for (int d = 8; d >= 1; d >>= 1) {
        pS += __shfl_down(pS, d, 16);
        pD += __shfl_down(pD, d, 16);
      }
      if (ok && m == 0) {
        aS[(unsigned)rowo * 4u + u] = pS * LOG2E;   // prescale: exp(e)=exp2(e*log2e)
        aD[(unsigned)rowo * 4u + u] = pD * LOG2E;
      }
    }
  }
}

// one wave per dst node; lane l = u*16+c owns cols (32u+c, 32u+c+16), head u.
// Scalar indices (s_load) + saddr gathers + 2-deep software pipeline.
__global__ __launch_bounds__(256) void k_aggregate(
    const unsigned int* __restrict__ hb, const float* __restrict__ aS, const float* __restrict__ aD,
    const int* __restrict__ off, const int* __restrict__ ssrc,
    const float* __restrict__ bias, float* __restrict__ out, int Nn) {
  int wave = threadIdx.x >> 6;
  int lane = threadIdx.x & 63;
  int node = blockIdx.x * 4 + wave;
  if (node >= Nn) return;
  int un = __builtin_amdgcn_readfirstlane(node);   // SGPR: wave-uniform
  unsigned hd = (unsigned)lane >> 4;
  float ad = aD[(unsigned)un * 4u + hd];
  int p0 = off[un], p1 = off[un + 1];              // uniform -> s_load
  const int* sp = ssrc + p0;                       // uniform pointer
  int deg = p1 - p0;
  int nch = deg >> 2;
  f32x2 acc = {0.f, 0.f};
  float denA = 0.f, denB = 0.f;

  int s0 = 0, s1 = 0, s2 = 0, s3 = 0;
  unsigned v0 = 0, v1 = 0, v2 = 0, v3 = 0;
  float a0 = 0.f, a1 = 0.f, a2 = 0.f, a3 = 0.f;
  if (nch > 0) {
    s0 = sp[0]; s1 = sp[1]; s2 = sp[2]; s3 = sp[3];
    v0 = hb[(unsigned)s0 * 64u + lane]; v1 = hb[(unsigned)s1 * 64u + lane];
    v2 = hb[(unsigned)s2 * 64u + lane]; v3 = hb[(unsigned)s3 * 64u + lane];
    a0 = aS[(unsigned)s0 * 4u + hd]; a1 = aS[(unsigned)s1 * 4u + hd];
    a2 = aS[(unsigned)s2 * 4u + hd]; a3 = aS[(unsigned)s3 * 4u + hd];
    sp += 4;
  }
  for (int c = 0; c < nch; ++c) {
    int t0 = 0, t1 = 0, t2 = 0, t3 = 0;
    unsigned w0 = 0, w1 = 0, w2 = 0, w3 = 0;
    float b0 = 0.f, b1 = 0.f, b2 = 0.f, b3 = 0.f;
    if (c + 1 < nch) {   // issue next chunk's loads before current math
      t0 = sp[0]; t1 = sp[1]; t2 = sp[2]; t3 = sp[3];
      w0 = hb[(unsigned)t0 * 64u + lane]; w1 = hb[(unsigned)t1 * 64u + lane];
      w2 = hb[(unsigned)t2 * 64u + lane]; w3 = hb[(unsigned)t3 * 64u + lane];
      b0 = aS[(unsigned)t0 * 4u + hd]; b1 = aS[(unsigned)t1 * 4u + hd];
      b2 = aS[(unsigned)t2 * 4u + hd]; b3 = aS[(unsigned)t3 * 4u + hd];
      sp += 4;
    }
    float e0 = a0 + ad, e1 = a1 + ad, e2 = a2 + ad, e3 = a3 + ad;
    e0 = fmaxf(e0, NEG_SLOPE * e0); e1 = fmaxf(e1, NEG_SLOPE * e1);
    e2 = fmaxf(e2, NEG_SLOPE * e2); e3 = fmaxf(e3, NEG_SLOPE * e3);
    float x0 = exp2f(e0), x1 = exp2f(e1), x2 = exp2f(e2), x3 = exp2f(e3);
    denA += x0 + x1; denB += x2 + x3;
    f32x2 h0 = { __uint_as_float(v0 << 16), __uint_as_float(v0 & 0xffff0000u) };
    f32x2 h1 = { __uint_as_float(v1 << 16), __uint_as_float(v1 & 0xffff0000u) };
    f32x2 h2 = { __uint_as_float(v2 << 16), __uint_as_float(v2 & 0xffff0000u) };
    f32x2 h3 = { __uint_as_float(v3 << 16), __uint_as_float(v3 & 0xffff0000u) };
    acc = h0 * x0 + acc;   // v_pk_fma_f32
    acc = h1 * x1 + acc;
    acc = h2 * x2 + acc;
    acc = h3 * x3 + acc;
    s0 = t0; s1 = t1; s2 = t2; s3 = t3;
    v0 = w0; v1 = w1; v2 = w2; v3 = w3;
    a0 = b0; a1 = b1; a2 = b2; a3 = b3;
  }
  for (int p = nch << 2; p < deg; ++p) {
    int src = (ssrc + p0)[p];                      // uniform -> s_load
    float e = aS[(unsigned)src * 4u + hd] + ad;
    e = fmaxf(e, NEG_SLOPE * e);
    float ex = exp2f(e);
    unsigned v = hb[(unsigned)src * 64u + lane];
    f32x2 hh = { __uint_as_float(v << 16), __uint_as_float(v & 0xffff0000u) };
    acc = hh * ex + acc;
    denA += ex;
  }
  float inv = 1.0f / (denA + denB + 1e-16f);
  unsigned col = hd * 32u + ((unsigned)lane & 15u);
  out[(unsigned)un * 128u + col] = acc.x * inv + bias[col];
  out[(unsigned)un * 128u + col + 16u] = acc.y * inv + bias[col + 16];
}

extern "C" void kernel_launch(void* const* d_in, const int* in_sizes, int n_in,
                              void* d_out, int out_size, void* d_ws, size_t ws_size,
                              hipStream_t stream) {
  const float* x    = (const float*)d_in[0];
  const int*   ei   = (const int*)d_in[1];
  const float* W    = (const float*)d_in[2];
  const float* attS = (const float*)d_in[3];
  const float* attD = (const float*)d_in[4];
  const float* bias = (const float*)d_in[5];
  float* out = (float*)d_out;

  const int Nn = in_sizes[0] / 128;
  const int E  = in_sizes[1] / 2;
  const int nbBin = (E + CHUNK - 1) / CHUNK;
  const int nSelf = (Nn + CHUNK - 1) / CHUNK;
  const int nGemm = (Nn + 63) / 64;

  char* ws = (char*)d_ws;
  size_t o = 0;
  auto take = [&](size_t bytes) { void* p = ws + o; o += (bytes + 255) & ~(size_t)255; return p; };
  int* off       = (int*)take((size_t)(Nn + 1) * 4);
  int* ssrc      = (int*)take((size_t)(E + Nn) * 4);
  int* deg       = (int*)take((size_t)Nn * 4);
  unsigned int* rank = (unsigned int*)take((size_t)E * 4);
  float* aS      = (float*)take((size_t)Nn * 4 * 4);
  float* aD      = (float*)take((size_t)Nn * 4 * 4);
  unsigned short* Wt = (unsigned short*)take((size_t)128 * 128 * 2);
  unsigned int* hb = (unsigned int*)take((size_t)Nn * 64 * 4);
  (void)ws_size; (void)o;

  hipMemsetAsync(deg, 0, (size_t)Nn * 4, stream);
  k_deg_prep<<<nbBin + 64, 256, 0, stream>>>(ei, deg, rank, E, W, Wt, nbBin);
  k_scan<<<1, 1024, 0, stream>>>(deg, off, Nn);
  k_scatmm<<<nbBin + nSelf + nGemm, 256, 0, stream>>>(ei, rank, off, ssrc, E, Nn,
                                                      nbBin, nSelf, x, Wt, hb,
                                                      attS, attD, aS, aD);
  k_aggregate<<<(Nn + 3) / 4, 256, 0, stream>>>(hb, aS, aD, off, ssrc, bias, out, Nn);
}

// Round 2
// 392.903 us; speedup vs baseline: 1.0687x; 1.0687x over previous
//
#include <hip/hip_runtime.h>

// GAT conv forward: N=100000 nodes, E=1.6M edges (+N self loops), IN_F=128,
// OUT_F=32, HEADS=4. Pipeline (R8, 6 dispatches) — atomic-rank CSR build with
// bucket-staged placement (R6 write locality + R7 atomic ranks, scan hidden):
//   1. memset deg+bucketCnt (adjacent)
//   2. k_deg_prep: rank[e]=atomicAdd(&deg[dst],1) + LDS coarse histogram
//      (dst>>9 -> bucketCnt) + W->W^T bf16 prep
//   3. k_bscan: 1-wave exclusive scan of 256 bucket counts -> bucketOff/bcur
//   4. k_scatbin (fat): block 0 = fine exclusive scan deg+1 -> off[] (HIDDEN
//      under other blocks; only k_place needs off); blocks [1,1+nbBin) = LDS
//      coarse binning of edges -> binned[] (src|dstLocal<<20) + brank[]
//      (global rank, ushort), bucket-grouped coalesced writes; blocks
//      [1+nbBin,..) = h=x@W mfma bf16 + fused a_src/a_dst epilogue, aS/aD
//      PRESCALED by log2(e).
//   5. k_place: 391 edge blocks read binned coalesced, write
//      ssrc[off[dst]+1+rank] (writes dense within <=2 bucket windows of 36KB
//      -> L2-friendly, no LDS sort, no atomics); +25 blocks self-loop heads.
//   6. k_aggregate: one wave per dst; scalar (SGPR) indices + saddr gathers,
//      2-deep software pipeline, f32x2 accumulate (v_pk_fma_f32), exp2f.
//      (unchanged from R6/R7 for attribution)

#define NEG_SLOPE 0.2f
#define NB_MAX 256      // coarse buckets (Nn <= 131072)
#define BSHIFT 9        // 512 nodes per bucket
#define CHUNK 4096      // edges per block
#define LOG2E 1.4426950408889634f

typedef __attribute__((ext_vector_type(8))) short short8;
typedef __attribute__((ext_vector_type(4))) float f32x4;
typedef __attribute__((ext_vector_type(2))) float f32x2;

__device__ __forceinline__ unsigned int rne16(unsigned int u) {
  return (u + 0x7fffu + ((u >> 16) & 1u)) >> 16;
}
__device__ __forceinline__ unsigned int f2bf_pack(float a, float b) {
  return (rne16(__float_as_uint(b)) << 16) | (rne16(__float_as_uint(a)) & 0xffffu);
}

// blocks [0,nbBin): deg/rank atomics + coarse hist; blocks [nbBin,+64): W^T
__global__ __launch_bounds__(256) void k_deg_prep(
    const int* __restrict__ ei, int* __restrict__ deg, unsigned int* __restrict__ rank,
    int* __restrict__ bucketCnt, int E,
    const float* __restrict__ W, unsigned short* __restrict__ Wt, int nbBin) {
  __shared__ int h[NB_MAX];
  int tid = threadIdx.x;
  if ((int)blockIdx.x >= nbBin) {
    int idx = (blockIdx.x - nbBin) * 256 + tid;   // 16384 total
    int k = idx >> 7, col = idx & 127;
    Wt[col * 128 + k] = (unsigned short)rne16(__float_as_uint(W[idx]));
    return;
  }
  h[tid] = 0;
  __syncthreads();
  int base = blockIdx.x * CHUNK;
  int n = E - base; if (n > CHUNK) n = CHUNK;
  for (int i = tid; i < n; i += 256) {
    int d = ei[E + base + i];
    rank[base + i] = (unsigned int)atomicAdd(&deg[d], 1);  // rank within dst
    atomicAdd(&h[d >> BSHIFT], 1);
  }
  __syncthreads();
  if (h[tid]) atomicAdd(&bucketCnt[tid], h[tid]);
}

// single wave: exclusive scan of 256 bucket counts -> bucketOff, bcur
__global__ void k_bscan(const int* __restrict__ bucketCnt,
                        int* __restrict__ bucketOff, int* __restrict__ bcur) {
  int lane = threadIdx.x;  // 64
  int base = lane * 4;
  int v0 = bucketCnt[base], v1 = bucketCnt[base + 1];
  int v2 = bucketCnt[base + 2], v3 = bucketCnt[base + 3];
  int s = v0 + v1 + v2 + v3;
  int inc = s;
#pragma unroll
  for (int d = 1; d < 64; d <<= 1) {
    int t = __shfl_up(inc, d, 64);
    if (lane >= d) inc += t;
  }
  int ex = inc - s;
  bucketOff[base] = ex;               bcur[base] = ex;
  bucketOff[base + 1] = ex + v0;      bcur[base + 1] = ex + v0;
  bucketOff[base + 2] = ex + v0 + v1; bcur[base + 2] = ex + v0 + v1;
  bucketOff[base + 3] = ex + v0 + v1 + v2; bcur[base + 3] = ex + v0 + v1 + v2;
  if (lane == 63) bucketOff[256] = inc;   // total E
}

// FAT kernel: fine-scan block + bin path + gemm(+att) path in one dispatch.
__global__ __launch_bounds__(256) void k_scatbin(
    const int* __restrict__ ei, const unsigned int* __restrict__ rank,
    int* __restrict__ bcur, unsigned int* __restrict__ binned,
    unsigned short* __restrict__ brank, int E, int Nn, int nb, int nbBin,
    const int* __restrict__ deg, int* __restrict__ off,
    const float* __restrict__ x, const unsigned short* __restrict__ Wt,
    unsigned int* __restrict__ hb,
    const float* __restrict__ attS, const float* __restrict__ attD,
    float* __restrict__ aS, float* __restrict__ aD) {
  __shared__ unsigned int buf[CHUNK];       // 16 KB packed src|dstLocal<<20
  __shared__ unsigned short rnk[CHUNK];     // 8 KB global rank per slot
  __shared__ unsigned char bkt[CHUNK];      // 4 KB bucket id per slot
  __shared__ int hist[NB_MAX];
  __shared__ int loc[NB_MAX];
  __shared__ int gbase[NB_MAX];
  __shared__ int wsum[4];
  int tid = threadIdx.x;
  int b = blockIdx.x;

  if (b == 0) {
    // ---------- fine exclusive scan of deg+1 -> off (hidden) ----------
    int lane = tid & 63, w = tid >> 6;
    int carry = 0;
    for (int base = 0; base < Nn; base += 4096) {
      int i0 = base + tid * 16;
      int v[16];
      int run = 0;
#pragma unroll
      for (int k = 0; k < 16; ++k) {
        int i = i0 + k;
        int d = (i < Nn) ? deg[i] + 1 : 0;   // +1: self loop per node
        v[k] = run; run += d;
      }
      int inc = run;
#pragma unroll
      for (int d = 1; d < 64; d <<= 1) {
        int t = __shfl_up(inc, d, 64);
        if (lane >= d) inc += t;
      }
      if (lane == 63) wsum[w] = inc;
      __syncthreads();
      int wbase = 0;
      for (int ww = 0; ww < w; ++ww) wbase += wsum[ww];
      int tot = wsum[0] + wsum[1] + wsum[2] + wsum[3];
      int ex = carry + wbase + inc - run;
#pragma unroll
      for (int k = 0; k < 16; ++k) {
        int i = i0 + k;
        if (i < Nn) off[i] = ex + v[k];
      }
      carry += tot;
      __syncthreads();
    }
    if (tid == 0) off[Nn] = carry;
    return;
  }

  if (b <= nbBin) {
    // ---------------- bin path ----------------
    int e0 = (b - 1) * CHUNK;
    int n = E - e0; if (n > CHUNK) n = CHUNK;

    for (int i = tid; i < NB_MAX; i += 256) hist[i] = 0;
    __syncthreads();

    int dstv[CHUNK / 256];
    int rankv[CHUNK / 256];
#pragma unroll
    for (int j = 0; j < CHUNK / 256; ++j) {
      int idx = j * 256 + tid;
      dstv[j] = -1;
      if (idx < n) {
        int d = ei[E + e0 + idx];
        dstv[j] = d;
        rankv[j] = atomicAdd(&hist[d >> BSHIFT], 1);
      }
    }
    __syncthreads();

    if (tid < 64) {
      int base = tid * 4;
      int v0 = hist[base], v1 = hist[base + 1], v2 = hist[base + 2], v3 = hist[base + 3];
      int s = v0 + v1 + v2 + v3;
      int inc = s;
#pragma unroll
      for (int d = 1; d < 64; d <<= 1) {
        int t = __shfl_up(inc, d, 64);
        if (tid >= d) inc += t;
      }
      int ex = inc - s;
      loc[base] = ex; loc[base + 1] = ex + v0;
      loc[base + 2] = ex + v0 + v1; loc[base + 3] = ex + v0 + v1 + v2;
    }
    __syncthreads();

#pragma unroll
    for (int j = 0; j < CHUNK / 256; ++j) {
      if (dstv[j] >= 0) {
        int e = e0 + j * 256 + tid;
        int src = ei[e];
        unsigned grk = rank[e];
        int b2 = dstv[j] >> BSHIFT;
        int slot = loc[b2] + rankv[j];
        buf[slot] = (unsigned)src | ((unsigned)(dstv[j] & 511) << 20);
        bkt[slot] = (unsigned char)b2;
        rnk[slot] = (unsigned short)grk;
      }
    }
    for (int b2 = tid; b2 < nb; b2 += 256)
      if (hist[b2] > 0) gbase[b2] = atomicAdd(&bcur[b2], hist[b2]);
    __syncthreads();

    for (int s = tid; s < n; s += 256) {
      int b2 = bkt[s];
      int o = gbase[b2] + (s - loc[b2]);
      binned[o] = buf[s];
      brank[o] = rnk[s];
    }
    return;
  }

  // ---------------- gemm + att path ----------------
  int gbid = b - 1 - nbBin;
  int w = tid >> 6, lane = tid & 63;
  int m = lane & 15, q = lane >> 4;
  int r0 = gbid * 64 + w * 16;
  int rowA = r0 + m; if (rowA >= Nn) rowA = Nn - 1;
  const float* xrow = x + (unsigned)rowA * 128u;

  f32x4 acc[8];
#pragma unroll
  for (int t = 0; t < 8; ++t) acc[t] = (f32x4){0.f, 0.f, 0.f, 0.f};

#pragma unroll
  for (int ks = 0; ks < 4; ++ks) {
    int k0 = ks * 32 + q * 8;
    float4 a0 = *(const float4*)(xrow + k0);
    float4 a1 = *(const float4*)(xrow + k0 + 4);
    unsigned au[4];
    au[0] = f2bf_pack(a0.x, a0.y);
    au[1] = f2bf_pack(a0.z, a0.w);
    au[2] = f2bf_pack(a1.x, a1.y);
    au[3] = f2bf_pack(a1.z, a1.w);
    short8 af = *(short8*)au;
#pragma unroll
    for (int t = 0; t < 8; ++t) {
      short8 bf = *(const short8*)(Wt + (unsigned)(t * 16 + m) * 128u + k0);
      acc[t] = __builtin_amdgcn_mfma_f32_16x16x32_bf16(af, bf, acc[t], 0, 0, 0);
    }
  }

  // att vector slices owned by this lane: head u cols 32u+m and 32u+m+16
  float sSa[4], sSb[4], sDa[4], sDb[4];
#pragma unroll
  for (int u = 0; u < 4; ++u) {
    sSa[u] = attS[u * 32 + m]; sSb[u] = attS[u * 32 + m + 16];
    sDa[u] = attD[u * 32 + m]; sDb[u] = attD[u * 32 + m + 16];
  }

  // C layout: col = m, row = q*4 + reg
#pragma unroll
  for (int r = 0; r < 4; ++r) {
    int rowo = r0 + q * 4 + r;
    bool ok = rowo < Nn;
    if (ok) {
#pragma unroll
      for (int u = 0; u < 4; ++u)
        hb[(unsigned)rowo * 64u + u * 16 + m] = f2bf_pack(acc[2 * u][r], acc[2 * u + 1][r]);
    }
#pragma unroll
    for (int u = 0; u < 4; ++u) {
      float pS = acc[2 * u][r] * sSa[u] + acc[2 * u + 1][r] * sSb[u];
      float pD = acc[2 * u][r] * sDa[u] + acc[2 * u + 1][r] * sDb[u];
#pragma unroll
      for (int d = 8; d >= 1; d >>= 1) {
        pS += __shfl_down(pS, d, 16);
        pD += __shfl_down(pD, d, 16);
      }
      if (ok && m == 0) {
        aS[(unsigned)rowo * 4u + u] = pS * LOG2E;   // prescale: exp(e)=exp2(e*log2e)
        aD[(unsigned)rowo * 4u + u] = pD * LOG2E;
      }
    }
  }
}

// blocks [0,npl): place binned edges -> ssrc (writes dense per bucket window);
// blocks [npl,+nSelf): self-loop heads.
__global__ __launch_bounds__(256) void k_place(
    const unsigned int* __restrict__ binned, const unsigned short* __restrict__ brank,
    const int* __restrict__ bucketOff, const int* __restrict__ off,
    int* __restrict__ ssrc, int E, int Nn, int nb, int npl) {
  __shared__ int bo[NB_MAX + 1];
  int tid = threadIdx.x;
  int b = blockIdx.x;
  if (b >= npl) {
    int i0 = (b - npl) * CHUNK;
    for (int i = tid; i < CHUNK; i += 256) {
      int node = i0 + i;
      if (node < Nn) ssrc[off[node]] = node;   // self loop at segment head
    }
    return;
  }
  for (int i = tid; i <= nb; i += 256) bo[i] = bucketOff[i];
  __syncthreads();
  int s0 = b * CHUNK;
  int n = E - s0; if (n > CHUNK) n = CHUNK;
  for (int i = tid; i < n; i += 256) {
    int s = s0 + i;
    // find bucket: bo[lo] <= s < bo[lo+1]
    int lo = 0, hi = nb;
    while (hi - lo > 1) { int mid = (lo + hi) >> 1; if (bo[mid] <= s) lo = mid; else hi = mid; }
    unsigned p = binned[s];
    int rk = brank[s];
    int dst = (lo << BSHIFT) + (int)((p >> 20) & 511u);
    ssrc[off[dst] + 1 + rk] = (int)(p & 0xFFFFFu);
  }
}

// one wave per dst node; lane l = u*16+c owns cols (32u+c, 32u+c+16), head u.
// Scalar indices (s_load) + saddr gathers + 2-deep software pipeline.
__global__ __launch_bounds__(256) void k_aggregate(
    const unsigned int* __restrict__ hb, const float* __restrict__ aS, const float* __restrict__ aD,
    const int* __restrict__ off, const int* __restrict__ ssrc,
    const float* __restrict__ bias, float* __restrict__ out, int Nn) {
  int wave = threadIdx.x >> 6;
  int lane = threadIdx.x & 63;
  int node = blockIdx.x * 4 + wave;
  if (node >= Nn) return;
  int un = __builtin_amdgcn_readfirstlane(node);   // SGPR: wave-uniform
  unsigned hd = (unsigned)lane >> 4;
  float ad = aD[(unsigned)un * 4u + hd];
  int p0 = off[un], p1 = off[un + 1];              // uniform -> s_load
  const int* sp = ssrc + p0;                       // uniform pointer
  int deg = p1 - p0;
  int nch = deg >> 2;
  f32x2 acc = {0.f, 0.f};
  float denA = 0.f, denB = 0.f;

  int s0 = 0, s1 = 0, s2 = 0, s3 = 0;
  unsigned v0 = 0, v1 = 0, v2 = 0, v3 = 0;
  float a0 = 0.f, a1 = 0.f, a2 = 0.f, a3 = 0.f;
  if (nch > 0) {
    s0 = sp[0]; s1 = sp[1]; s2 = sp[2]; s3 = sp[3];
    v0 = hb[(unsigned)s0 * 64u + lane]; v1 = hb[(unsigned)s1 * 64u + lane];
    v2 = hb[(unsigned)s2 * 64u + lane]; v3 = hb[(unsigned)s3 * 64u + lane];
    a0 = aS[(unsigned)s0 * 4u + hd]; a1 = aS[(unsigned)s1 * 4u + hd];
    a2 = aS[(unsigned)s2 * 4u + hd]; a3 = aS[(unsigned)s3 * 4u + hd];
    sp += 4;
  }
  for (int c = 0; c < nch; ++c) {
    int t0 = 0, t1 = 0, t2 = 0, t3 = 0;
    unsigned w0 = 0, w1 = 0, w2 = 0, w3 = 0;
    float b0 = 0.f, b1 = 0.f, b2 = 0.f, b3 = 0.f;
    if (c + 1 < nch) {   // issue next chunk's loads before current math
      t0 = sp[0]; t1 = sp[1]; t2 = sp[2]; t3 = sp[3];
      w0 = hb[(unsigned)t0 * 64u + lane]; w1 = hb[(unsigned)t1 * 64u + lane];
      w2 = hb[(unsigned)t2 * 64u + lane]; w3 = hb[(unsigned)t3 * 64u + lane];
      b0 = aS[(unsigned)t0 * 4u + hd]; b1 = aS[(unsigned)t1 * 4u + hd];
      b2 = aS[(unsigned)t2 * 4u + hd]; b3 = aS[(unsigned)t3 * 4u + hd];
      sp += 4;
    }
    float e0 = a0 + ad, e1 = a1 + ad, e2 = a2 + ad, e3 = a3 + ad;
    e0 = fmaxf(e0, NEG_SLOPE * e0); e1 = fmaxf(e1, NEG_SLOPE * e1);
    e2 = fmaxf(e2, NEG_SLOPE * e2); e3 = fmaxf(e3, NEG_SLOPE * e3);
    float x0 = exp2f(e0), x1 = exp2f(e1), x2 = exp2f(e2), x3 = exp2f(e3);
    denA += x0 + x1; denB += x2 + x3;
    f32x2 h0 = { __uint_as_float(v0 << 16), __uint_as_float(v0 & 0xffff0000u) };
    f32x2 h1 = { __uint_as_float(v1 << 16), __uint_as_float(v1 & 0xffff0000u) };
    f32x2 h2 = { __uint_as_float(v2 << 16), __uint_as_float(v2 & 0xffff0000u) };
    f32x2 h3 = { __uint_as_float(v3 << 16), __uint_as_float(v3 & 0xffff0000u) };
    acc = h0 * x0 + acc;   // v_pk_fma_f32
    acc = h1 * x1 + acc;
    acc = h2 * x2 + acc;
    acc = h3 * x3 + acc;
    s0 = t0; s1 = t1; s2 = t2; s3 = t3;
    v0 = w0; v1 = w1; v2 = w2; v3 = w3;
    a0 = b0; a1 = b1; a2 = b2; a3 = b3;
  }
  for (int p = nch << 2; p < deg; ++p) {
    int src = (ssrc + p0)[p];                      // uniform -> s_load
    float e = aS[(unsigned)src * 4u + hd] + ad;
    e = fmaxf(e, NEG_SLOPE * e);
    float ex = exp2f(e);
    unsigned v = hb[(unsigned)src * 64u + lane];
    f32x2 hh = { __uint_as_float(v << 16), __uint_as_float(v & 0xffff0000u) };
    acc = hh * ex + acc;
    denA += ex;
  }
  float inv = 1.0f / (denA + denB + 1e-16f);
  unsigned col = hd * 32u + ((unsigned)lane & 15u);
  out[(unsigned)un * 128u + col] = acc.x * inv + bias[col];
  out[(unsigned)un * 128u + col + 16u] = acc.y * inv + bias[col + 16];
}

extern "C" void kernel_launch(void* const* d_in, const int* in_sizes, int n_in,
                              void* d_out, int out_size, void* d_ws, size_t ws_size,
                              hipStream_t stream) {
  const float* x    = (const float*)d_in[0];
  const int*   ei   = (const int*)d_in[1];
  const float* W    = (const float*)d_in[2];
  const float* attS = (const float*)d_in[3];
  const float* attD = (const float*)d_in[4];
  const float* bias = (const float*)d_in[5];
  float* out = (float*)d_out;

  const int Nn = in_sizes[0] / 128;
  const int E  = in_sizes[1] / 2;
  const int nb = (Nn + (1 << BSHIFT) - 1) >> BSHIFT;
  const int nbBin = (E + CHUNK - 1) / CHUNK;
  const int nSelf = (Nn + CHUNK - 1) / CHUNK;
  const int nGemm = (Nn + 63) / 64;

  char* ws = (char*)d_ws;
  size_t o = 0;
  auto take = [&](size_t bytes) { void* p = ws + o; o += (bytes + 255) & ~(size_t)255; return p; };
  int* off       = (int*)take((size_t)(Nn + 1) * 4);
  int* ssrc      = (int*)take((size_t)(E + Nn) * 4);
  int* deg       = (int*)take((size_t)(Nn + NB_MAX) * 4);  // deg + bucketCnt, one memset
  int* bucketCnt = deg + Nn;
  int* bucketOff = (int*)take((size_t)(NB_MAX + 1) * 4);
  int* bcur      = (int*)take((size_t)NB_MAX * 4);
  unsigned int* rank = (unsigned int*)take((size_t)E * 4);
  unsigned short* brank = (unsigned short*)take((size_t)E * 2);
  float* aS      = (float*)take((size_t)Nn * 4 * 4);
  float* aD      = (float*)take((size_t)Nn * 4 * 4);
  unsigned short* Wt = (unsigned short*)take((size_t)128 * 128 * 2);
  unsigned int* hb = (unsigned int*)take((size_t)Nn * 64 * 4);
  unsigned int* binned = (unsigned int*)take((size_t)E * 4);
  (void)ws_size; (void)o;

  hipMemsetAsync(deg, 0, (size_t)(Nn + NB_MAX) * 4, stream);
  k_deg_prep<<<nbBin + 64, 256, 0, stream>>>(ei, deg, rank, bucketCnt, E, W, Wt, nbBin);
  k_bscan<<<1, 64, 0, stream>>>(bucketCnt, bucketOff, bcur);
  k_scatbin<<<1 + nbBin + nGemm, 256, 0, stream>>>(ei, rank, bcur, binned, brank,
                                                   E, Nn, nb, nbBin, deg, off,
                                                   x, Wt, hb, attS, attD, aS, aD);
  k_place<<<nbBin + nSelf, 256, 0, stream>>>(binned, brank, bucketOff, off, ssrc,
                                             E, Nn, nb, nbBin);
  k_aggregate<<<(Nn + 3) / 4, 256, 0, stream>>>(hb, aS, aD, off, ssrc, bias, out, Nn);
}